// Round 17
// baseline (332.010 us; speedup 1.0000x reference)
//
#include <hip/hip_runtime.h>
#include <hip/hip_fp16.h>

#define TPB 256
#define NBLK1 256          // CSR pass-1 blocks
#define BSH 10             // bucket shift: 1024 nodes per bucket (NB <= 128)
#define MAXBE 12288        // max edges/bucket -> 48KB LDS
#define KS 8               // head GEMM K-splits
#define GB 8               // head GEMM graphs per block
#define NPB 42             // gconv2 nodes/block (42*6 = 252 <= 256)

static inline int cdiv(long long a, int b){ return (int)((a + b - 1)/b); }

// 8 halves = 16 bytes, 16-byte aligned -> single dwordx4 loads
struct __align__(16) h8 { __half2 a, b, c, d; };
struct float8 { float4 lo, hi; };
__device__ inline float8 h8tof8(h8 v){
    float2 t0 = __half22float2(v.a), t1 = __half22float2(v.b);
    float2 t2 = __half22float2(v.c), t3 = __half22float2(v.d);
    float8 r;
    r.lo = make_float4(t0.x, t0.y, t1.x, t1.y);
    r.hi = make_float4(t2.x, t2.y, t3.x, t3.y);
    return r;
}
__device__ inline h8 f8toh8(float8 v){
    h8 r;
    r.a = __floats2half2_rn(v.lo.x, v.lo.y); r.b = __floats2half2_rn(v.lo.z, v.lo.w);
    r.c = __floats2half2_rn(v.hi.x, v.hi.y); r.d = __floats2half2_rn(v.hi.z, v.hi.w);
    return r;
}
__device__ inline void f8acc(float8& a, float8 v){
    a.lo.x += v.lo.x; a.lo.y += v.lo.y; a.lo.z += v.lo.z; a.lo.w += v.lo.w;
    a.hi.x += v.hi.x; a.hi.y += v.hi.y; a.hi.z += v.hi.z; a.hi.w += v.hi.w;
}

// ---------- kernel 1: bucket count (blocks 0..NBLK1) + head split-K GEMM (rest) ----------
// Independent workloads merged to save a kernel boundary.
__global__ void k_bcnt_head(const int* __restrict__ dst, int* __restrict__ cnt_t,
                            int E, int NB, int chunk,
                            const float* __restrict__ feature, const float* __restrict__ Wf1,
                            float* __restrict__ partial, int G, int FEAT, int H){
    __shared__ int hist[128];
    __shared__ float sfeat[128*GB];
    int t = threadIdx.x;
    if(blockIdx.x < NBLK1){
        // ---- bucket count ----
        int blk = blockIdx.x;
        for(int i = t; i < NB; i += blockDim.x) hist[i] = 0;
        __syncthreads();
        int lo = blk*chunk, hi = min(E, lo + chunk);
        for(int e = lo + t; e < hi; e += blockDim.x)
            atomicAdd(&hist[dst[e] >> BSH], 1);
        __syncthreads();
        for(int b = t; b < NB; b += blockDim.x)
            cnt_t[blk*NB + b] = hist[b];
    } else {
        // ---- head split-K GEMM: partial[ks][g][h] ----
        int bid = (int)blockIdx.x - NBLK1;          // 0..1023
        int g0 = (bid & 127)*GB;
        int ks = bid >> 7;
        int Kc = (FEAT + KS - 1)/KS;
        int k0 = ks*Kc;
        int k1 = min(FEAT, k0 + Kc);
        int kc = k1 - k0;
        for(int idx = t; idx < GB*128; idx += 256){
            int gi = idx >> 7, kk = idx & 127;
            if(kk < kc) sfeat[kk*GB + gi] = feature[(size_t)(g0+gi)*FEAT + k0 + kk];
        }
        __syncthreads();
        int h  = t & 127;
        int gq = t >> 7;
        const float* wp = Wf1 + (size_t)k0*H + h;
        float4 a = {0.f,0.f,0.f,0.f};
        const float4* sf = (const float4*)(sfeat) + gq;
        for(int kk = 0; kk < kc; kk++){
            float w = wp[(size_t)kk*H];
            float4 f = sf[kk*2];
            a.x += f.x*w; a.y += f.y*w; a.z += f.z*w; a.w += f.w*w;
        }
        float* pp = partial + ((size_t)ks*G + g0 + gq*4)*H + h;
        pp[0] = a.x; pp[H] = a.y; pp[2*H] = a.z; pp[3*H] = a.w;
    }
}

// scatter with inline prefix: pairs[pos] = (local_dst<<17)|src  (needs N < 2^17)
__global__ void k_bscatter(const int* __restrict__ ei, const int* __restrict__ cnt_t,
                           int* __restrict__ pairs, int E, int NB, int chunk){
    __shared__ int cur[128];
    __shared__ int st[128];
    int blk = blockIdx.x;
    int t = threadIdx.x;
    int myp = 0, myt = 0;
    for(int b2 = 0; b2 < NBLK1; b2++){
        int v = (t < NB) ? cnt_t[b2*NB + t] : 0;
        myp += (b2 < blk) ? v : 0;
        myt += v;
    }
    if(t < NB){ cur[t] = myp; st[t] = myt; }
    __syncthreads();
    if(t == 0){
        int run = 0;
        for(int b = 0; b < NB; b++){ int v = st[b]; st[b] = run; run += v; }
    }
    __syncthreads();
    if(t < NB) cur[t] += st[t];
    __syncthreads();
    int lo = blk*chunk, hi = min(E, lo + chunk);
    for(int e = lo + t; e < hi; e += blockDim.x){
        int s = ei[e], d = ei[E + e];
        int pos = atomicAdd(&cur[d >> BSH], 1);          // LDS atomic
        pairs[pos] = ((d & ((1 << BSH) - 1)) << 17) | s; // packed
    }
}

__global__ void k_build(const int* __restrict__ pairs, const int* __restrict__ cnt_t,
                        int* __restrict__ csr, int* __restrict__ cursor,
                        float* __restrict__ dinv, int* __restrict__ order,
                        int N, int E, int NB){
    __shared__ int stot[128];
    __shared__ int sBase, sCnt;
    __shared__ int c[1024];
    __shared__ int so[1024];
    __shared__ int part[256];
    __shared__ int csrl[MAXBE];
    int b = blockIdx.x;
    int t = threadIdx.x;
    int myt = 0;
    for(int b2 = 0; b2 < NBLK1; b2++)
        myt += (t < NB) ? cnt_t[b2*NB + t] : 0;
    if(t < NB) stot[t] = myt;
    __syncthreads();
    if(t == 0){
        int run = 0;
        for(int bb = 0; bb < NB; bb++){
            if(bb == b){ sBase = run; sCnt = stot[bb]; }
            run += stot[bb];
        }
    }
    __syncthreads();
    int base = sBase, cntE = sCnt;
    int n0 = b << BSH;
    int nn = min(1 << BSH, N - n0);

    for(int i = t; i < 1024; i += 256) c[i] = 0;
    __syncthreads();
    for(int i = t; i < cntE; i += 256)
        atomicAdd(&c[pairs[base + i] >> 17], 1);   // LDS atomic
    __syncthreads();
    int i0 = t*4;
    int l0 = c[i0], l1 = c[i0+1], l2 = c[i0+2], l3 = c[i0+3];
    part[t] = l0 + l1 + l2 + l3;
    __syncthreads();
    for(int off = 1; off < 256; off <<= 1){
        int u = (t >= off) ? part[t-off] : 0;
        __syncthreads();
        part[t] += u;
        __syncthreads();
    }
    int run = (t == 0) ? 0 : part[t-1];
    so[i0] = run; so[i0+1] = run + l0; so[i0+2] = run + l0 + l1; so[i0+3] = run + l0 + l1 + l2;
    __syncthreads();
    for(int i = t; i < nn; i += 256){
        int cc = c[i];
        cursor[n0 + i] = base + so[i] + cc;        // inclusive end offset
        dinv[n0 + i]   = rsqrtf((float)(cc + 1));  // +1 = self-loop
    }
    __syncthreads();
    // ---- degree-sort nodes within bucket (64-bin counting sort) -> order[] ----
    if(t < 64) part[t] = 0;
    __syncthreads();
    for(int i = t; i < nn; i += 256) atomicAdd(&part[min(c[i], 63)], 1);
    __syncthreads();
    if(t == 0){
        int r2 = 0;
        for(int k = 0; k < 64; k++){ int v = part[k]; part[k] = r2; r2 += v; }
    }
    __syncthreads();
    for(int i = t; i < nn; i += 256){
        int pos = atomicAdd(&part[min(c[i], 63)], 1);
        order[n0 + pos] = n0 + i;
    }
    __syncthreads();
    // ---- fill CSR via LDS staging ----
    for(int i = t; i < 1024; i += 256) c[i] = so[i];
    __syncthreads();
    for(int i = t; i < cntE; i += 256){
        int v = pairs[base + i];
        int pos = atomicAdd(&c[v >> 17], 1);       // LDS atomic
        csrl[pos] = v & 0x1FFFF;
    }
    __syncthreads();
    for(int i = t; i < cntE; i += 256) csr[base + i] = csrl[i];   // coalesced
}

// ---------- gather core: self + neighbor sum of one 16B chunk ----------
__device__ inline float8 gather_row(const int* __restrict__ cursor,
                                    const int* __restrict__ csr,
                                    const h8* __restrict__ t, int d, int cg){
    int start = (d == 0) ? 0 : cursor[d-1];
    int end   = cursor[d];
    float8 a0 = h8tof8(t[(size_t)d*6 + cg]);     // self-loop
    float8 a1 = {{0,0,0,0},{0,0,0,0}}, a2 = a1, a3 = a1;
    int j = start;
    for(; j + 8 <= end; j += 8){
        int s0 = csr[j],   s1 = csr[j+1], s2 = csr[j+2], s3 = csr[j+3];
        int s4 = csr[j+4], s5 = csr[j+5], s6 = csr[j+6], s7 = csr[j+7];
        h8 r0 = t[(size_t)s0*6 + cg];            // 8 independent dwordx4 in flight
        h8 r1 = t[(size_t)s1*6 + cg];
        h8 r2 = t[(size_t)s2*6 + cg];
        h8 r3 = t[(size_t)s3*6 + cg];
        h8 r4 = t[(size_t)s4*6 + cg];
        h8 r5 = t[(size_t)s5*6 + cg];
        h8 r6 = t[(size_t)s6*6 + cg];
        h8 r7 = t[(size_t)s7*6 + cg];
        f8acc(a0, h8tof8(r0)); f8acc(a1, h8tof8(r1));
        f8acc(a2, h8tof8(r2)); f8acc(a3, h8tof8(r3));
        f8acc(a0, h8tof8(r4)); f8acc(a1, h8tof8(r5));
        f8acc(a2, h8tof8(r6)); f8acc(a3, h8tof8(r7));
    }
    for(; j + 4 <= end; j += 4){
        int s0 = csr[j], s1 = csr[j+1], s2 = csr[j+2], s3 = csr[j+3];
        h8 r0 = t[(size_t)s0*6 + cg];
        h8 r1 = t[(size_t)s1*6 + cg];
        h8 r2 = t[(size_t)s2*6 + cg];
        h8 r3 = t[(size_t)s3*6 + cg];
        f8acc(a0, h8tof8(r0)); f8acc(a1, h8tof8(r1));
        f8acc(a2, h8tof8(r2)); f8acc(a3, h8tof8(r3));
    }
    for(; j < end; j++) f8acc(a0, h8tof8(t[(size_t)csr[j]*6 + cg]));
    f8acc(a0, a1); f8acc(a2, a3); f8acc(a0, a2);
    return a0;
}

// ---------- conv1 GEMM, row-batched x4: t = dinv .* (x @ W1) ----------
__global__ void k_gemm1r(const float* __restrict__ x, const float* __restrict__ W,
                         h8* __restrict__ t, int n, const float* __restrict__ dinv){
    __shared__ float sW[44*48];                   // [k][48], zero-padded cols
    for(int i = threadIdx.x; i < 44*48; i += blockDim.x){
        int k = i/48, j = i - k*48;
        sW[i] = (j < 44) ? W[k*44 + j] : 0.f;
    }
    __syncthreads();
    int nrg = (n + 3) >> 2;
    unsigned total = (unsigned)nrg * 6u;
    unsigned idx = blockIdx.x*blockDim.x + threadIdx.x;
    if(idx >= total) return;
    unsigned rg = idx / 6u;
    unsigned cg = idx - rg*6u;
    int row0 = (int)rg*4;
    const float4* sWv = (const float4*)sW;        // 12 float4 per k
    float8 acc[4] = {{{0,0,0,0},{0,0,0,0}},{{0,0,0,0},{0,0,0,0}},
                     {{0,0,0,0},{0,0,0,0}},{{0,0,0,0},{0,0,0,0}}};
    for(int k4 = 0; k4 < 11; k4++){
        float fv[4][4];
        #pragma unroll
        for(int r = 0; r < 4; r++){
            int rr = min(row0 + r, n - 1);        // clamp (tail rows duplicate, store guarded)
            *(float4*)fv[r] = ((const float4*)(x + (size_t)rr*44))[k4];
        }
        int kb = k4*4;
        #pragma unroll
        for(int i = 0; i < 4; i++){
            float4 wlo = sWv[(unsigned)(kb+i)*12 + cg*2];
            float4 whi = sWv[(unsigned)(kb+i)*12 + cg*2 + 1];
            #pragma unroll
            for(int r = 0; r < 4; r++){
                float h = fv[r][i];
                acc[r].lo.x += h*wlo.x; acc[r].lo.y += h*wlo.y;
                acc[r].lo.z += h*wlo.z; acc[r].lo.w += h*wlo.w;
                acc[r].hi.x += h*whi.x; acc[r].hi.y += h*whi.y;
                acc[r].hi.z += h*whi.z; acc[r].hi.w += h*whi.w;
            }
        }
    }
    #pragma unroll
    for(int r = 0; r < 4; r++){
        int row = row0 + r;
        if(row < n){
            float dd = dinv[row];
            acc[r].lo.x *= dd; acc[r].lo.y *= dd; acc[r].lo.z *= dd; acc[r].lo.w *= dd;
            acc[r].hi.x *= dd; acc[r].hi.y *= dd; acc[r].hi.z *= dd; acc[r].hi.w *= dd;
            t[(size_t)row*6 + cg] = f8toh8(acc[r]);
        }
    }
}

// ---------- plain gather (degree-ordered): out = [prescale][relu-if-bias](dinv*agg [+ bias]) ----------
__global__ void k_gather8(const int* __restrict__ cursor, const int* __restrict__ csr,
                          const int* __restrict__ order,
                          const h8* __restrict__ t, const float* __restrict__ dinv,
                          const float* __restrict__ bias, h8* __restrict__ out,
                          int n, int prescale_out){
    __shared__ float sb[48];
    if(threadIdx.x < 48) sb[threadIdx.x] = (bias && threadIdx.x < 44) ? bias[threadIdx.x] : 0.f;
    __syncthreads();
    unsigned total  = (unsigned)n * 6u;
    unsigned stride = gridDim.x * blockDim.x;
    const float4* sb4 = (const float4*)sb;
    for(unsigned idx = blockIdx.x*blockDim.x + threadIdx.x; idx < total; idx += stride){
        unsigned i  = idx / 6u;
        unsigned cg = idx - i*6u;
        int d = order[i];                     // degree-sorted processing order
        float8 acc = gather_row(cursor, csr, t, d, (int)cg);
        float dd = dinv[d];
        float4 blo = sb4[cg*2], bhi = sb4[cg*2+1];
        acc.lo.x = acc.lo.x*dd + blo.x; acc.lo.y = acc.lo.y*dd + blo.y;
        acc.lo.z = acc.lo.z*dd + blo.z; acc.lo.w = acc.lo.w*dd + blo.w;
        acc.hi.x = acc.hi.x*dd + bhi.x; acc.hi.y = acc.hi.y*dd + bhi.y;
        acc.hi.z = acc.hi.z*dd + bhi.z; acc.hi.w = acc.hi.w*dd + bhi.w;
        if(bias){
            acc.lo.x = fmaxf(acc.lo.x, 0.f); acc.lo.y = fmaxf(acc.lo.y, 0.f);
            acc.lo.z = fmaxf(acc.lo.z, 0.f); acc.lo.w = fmaxf(acc.lo.w, 0.f);
            acc.hi.x = fmaxf(acc.hi.x, 0.f); acc.hi.y = fmaxf(acc.hi.y, 0.f);
            acc.hi.z = fmaxf(acc.hi.z, 0.f); acc.hi.w = fmaxf(acc.hi.w, 0.f);
        }
        if(prescale_out){
            acc.lo.x *= dd; acc.lo.y *= dd; acc.lo.z *= dd; acc.lo.w *= dd;
            acc.hi.x *= dd; acc.hi.y *= dd; acc.hi.z *= dd; acc.hi.w *= dd;
        }
        out[(size_t)d*6 + cg] = f8toh8(acc);
    }
}

// ---------- fused conv2 + conv3-transform (round-14 structure — do not touch) ----------
__global__ void k_gconv2(const int* __restrict__ cursor, const int* __restrict__ csr,
                         const h8* __restrict__ tin, const float* __restrict__ dinv,
                         const float* __restrict__ W2, const float* __restrict__ b2,
                         const float* __restrict__ W3, h8* __restrict__ tout, int N){
    __shared__ float sW[44*88];     // W2 [44][88]; later reused for W3 [88][44]
    __shared__ float sb2[88];
    __shared__ float sAgg[NPB*49];
    __shared__ float sH2[NPB*89];
    __shared__ float sDinv[NPB];
    int t  = threadIdx.x;
    int d0 = blockIdx.x*NPB;
    int nn = min(NPB, N - d0);

    for(int i = t; i < 44*88; i += 256) sW[i] = W2[i];
    if(t < 88) sb2[t] = b2[t];
    __syncthreads();

    // phase 1: gather (6 threads per node)
    int ln = t/6, c = t - ln*6;
    if(t < NPB*6 && ln < nn){
        int d = d0 + ln;
        float8 acc = gather_row(cursor, csr, tin, d, c);
        float dd = dinv[d];
        if(c == 0) sDinv[ln] = dd;
        float* ar = sAgg + ln*49 + c*8;
        ar[0] = acc.lo.x*dd; ar[1] = acc.lo.y*dd; ar[2] = acc.lo.z*dd; ar[3] = acc.lo.w*dd;
        ar[4] = acc.hi.x*dd; ar[5] = acc.hi.y*dd; ar[6] = acc.hi.z*dd; ar[7] = acc.hi.w*dd;
    }
    __syncthreads();

    // phase 2: h2 = relu(t2 @ W2 + b2), float4-col chunks (22 per node)
    {
        const float4* sW4  = (const float4*)sW;    // 22 float4 per k
        const float4* sb24 = (const float4*)sb2;
        for(int o = t; o < nn*22; o += 256){
            int n_ = o/22, c4 = o - n_*22;
            const float* ar = sAgg + n_*49;
            float4 s = sb24[c4];
            for(int k = 0; k < 44; k++){
                float a = ar[k];
                float4 w = sW4[(unsigned)k*22 + c4];
                s.x += a*w.x; s.y += a*w.y; s.z += a*w.z; s.w += a*w.w;
            }
            float* hp = sH2 + n_*89 + c4*4;        // scalar stores (odd stride)
            hp[0] = fmaxf(s.x, 0.f); hp[1] = fmaxf(s.y, 0.f);
            hp[2] = fmaxf(s.z, 0.f); hp[3] = fmaxf(s.w, 0.f);
        }
    }
    __syncthreads();
    // restage W3 (88 x 44)
    for(int i = t; i < 88*44; i += 256) sW[i] = W3[i];
    __syncthreads();

    // phase 3: t3 = dinv * (h2 @ W3); one h8 chunk per thread
    {
        const float4* sW4 = (const float4*)sW;     // 11 float4 per k
        for(int o = t; o < nn*6; o += 256){
            int n_ = o/6, cc = o - n_*6;
            const float* hr = sH2 + n_*89;
            float dd = sDinv[n_];
            float4 slo = {0,0,0,0}, shi = {0,0,0,0};
            if(cc < 5){
                for(int k = 0; k < 88; k++){
                    float h = hr[k];
                    float4 wlo = sW4[(unsigned)k*11 + cc*2];
                    float4 whi = sW4[(unsigned)k*11 + cc*2 + 1];
                    slo.x += h*wlo.x; slo.y += h*wlo.y; slo.z += h*wlo.z; slo.w += h*wlo.w;
                    shi.x += h*whi.x; shi.y += h*whi.y; shi.z += h*whi.z; shi.w += h*whi.w;
                }
            } else {                                // cols 40..43 valid, 44..47 pad=0
                for(int k = 0; k < 88; k++){
                    float h = hr[k];
                    float4 wlo = sW4[(unsigned)k*11 + 10];
                    slo.x += h*wlo.x; slo.y += h*wlo.y; slo.z += h*wlo.z; slo.w += h*wlo.w;
                }
            }
            float8 acc;
            acc.lo = make_float4(slo.x*dd, slo.y*dd, slo.z*dd, slo.w*dd);
            acc.hi = make_float4(shi.x*dd, shi.y*dd, shi.z*dd, shi.w*dd);
            tout[(size_t)(d0+n_)*6 + cc] = f8toh8(acc);
        }
    }
}

// fused pool + epilogue: 4 graphs/block (one wave each).
__global__ void k_headfin(const float* __restrict__ partial, const float* __restrict__ bf1,
                          const float* __restrict__ Wf2, const float* __restrict__ bf2,
                          const h8* __restrict__ hbuf, const int* __restrict__ batch,
                          const float* __restrict__ Wg, const float* __restrict__ bg,
                          float* __restrict__ out, int G, int H, int n){
    int g    = blockIdx.x*4 + (threadIdx.x >> 6);
    int lane = threadIdx.x & 63;

    // segment bounds (batch sorted, non-empty)
    int lo = 0, hi = n;
    while(lo < hi){ int mid = (lo + hi) >> 1; if(batch[mid] < g) lo = mid + 1; else hi = mid; }
    int start = lo;
    hi = n;
    while(lo < hi){ int mid = (lo + hi) >> 1; if(batch[mid] < g + 1) lo = mid + 1; else hi = mid; }
    int end = lo;

    int rg = lane >> 3;          // 0..7 row groups
    int cg = lane & 7;           // 0..7 chunk slots, active < 6
    float8 m = {{0,0,0,0},{0,0,0,0}};    // valid floor: post-ReLU inputs
    if(cg < 6){
        for(int r = start + rg; r < end; r += 8){
            float8 v = h8tof8(hbuf[(size_t)r*6 + cg]);
            m.lo.x = fmaxf(m.lo.x, v.lo.x); m.lo.y = fmaxf(m.lo.y, v.lo.y);
            m.lo.z = fmaxf(m.lo.z, v.lo.z); m.lo.w = fmaxf(m.lo.w, v.lo.w);
            m.hi.x = fmaxf(m.hi.x, v.hi.x); m.hi.y = fmaxf(m.hi.y, v.hi.y);
            m.hi.z = fmaxf(m.hi.z, v.hi.z); m.hi.w = fmaxf(m.hi.w, v.hi.w);
        }
    }
    for(int off = 8; off <= 32; off <<= 1){
        m.lo.x = fmaxf(m.lo.x, __shfl_xor(m.lo.x, off, 64));
        m.lo.y = fmaxf(m.lo.y, __shfl_xor(m.lo.y, off, 64));
        m.lo.z = fmaxf(m.lo.z, __shfl_xor(m.lo.z, off, 64));
        m.lo.w = fmaxf(m.lo.w, __shfl_xor(m.lo.w, off, 64));
        m.hi.x = fmaxf(m.hi.x, __shfl_xor(m.hi.x, off, 64));
        m.hi.y = fmaxf(m.hi.y, __shfl_xor(m.hi.y, off, 64));
        m.hi.z = fmaxf(m.hi.z, __shfl_xor(m.hi.z, off, 64));
        m.hi.w = fmaxf(m.hi.w, __shfl_xor(m.hi.w, off, 64));
    }
    // x1 partial dot (only rg==0 lanes contribute; cols 44..47 are pad)
    float v = 0.f;
    if(rg == 0 && cg < 6){
        int base = cg*8;
        v = m.lo.x*Wg[base] + m.lo.y*Wg[base+1] + m.lo.z*Wg[base+2] + m.lo.w*Wg[base+3];
        if(cg < 5)
            v += m.hi.x*Wg[base+4] + m.hi.y*Wg[base+5] + m.hi.z*Wg[base+6] + m.hi.w*Wg[base+7];
    }

    // x2: combine split-K partials
    int h2 = lane;
    float2 s = {0.f, 0.f};
    for(int ks = 0; ks < KS; ks++){
        float2 p = ((const float2*)(partial + ((size_t)ks*G + g)*H))[h2];
        s.x += p.x; s.y += p.y;
    }
    float2 b  = ((const float2*)bf1)[h2];
    float2 w2 = ((const float2*)Wf2)[h2];
    float y = fmaxf(s.x + b.x, 0.f)*w2.x + fmaxf(s.y + b.y, 0.f)*w2.y;

    for(int off = 32; off; off >>= 1){
        y += __shfl_xor(y, off, 64);
        v += __shfl_xor(v, off, 64);
    }
    if(lane == 0) out[g] = fmaxf(v + bg[0], 0.f) + y + bf2[0];
}

extern "C" void kernel_launch(void* const* d_in, const int* in_sizes, int n_in,
                              void* d_out, int out_size, void* d_ws, size_t ws_size,
                              hipStream_t stream) {
    const float* x       = (const float*)d_in[0];
    const int*   ei      = (const int*)  d_in[1];
    const int*   batch   = (const int*)  d_in[2];
    const float* feature = (const float*)d_in[3];
    const float* W1 = (const float*)d_in[4];  const float* b1 = (const float*)d_in[5];
    const float* W2 = (const float*)d_in[6];  const float* b2 = (const float*)d_in[7];
    const float* W3 = (const float*)d_in[8];  const float* b3 = (const float*)d_in[9];
    const float* Wg = (const float*)d_in[10]; const float* bg = (const float*)d_in[11];
    const float* Wf1= (const float*)d_in[12]; const float* bf1= (const float*)d_in[13];
    const float* Wf2= (const float*)d_in[14]; const float* bf2= (const float*)d_in[15];
    float* out = (float*)d_out;

    const int N    = in_sizes[2];          // 100000 (< 2^17 required by pair packing)
    const int E    = in_sizes[1] / 2;      // 1000000
    const int G    = out_size;             // 1024
    const int FEAT = in_sizes[3] / G;      // 1019
    const int H    = in_sizes[13];         // 128

    const int NB    = cdiv(N, 1 << BSH);   // 98 coarse buckets
    const int chunk = cdiv(E, NBLK1);
    const int NRG   = cdiv(N, 4);

    // workspace layout (4B units)
    float* wsf    = (float*)d_ws;
    float* dinv   = wsf;                          // N floats
    int*   cursor = (int*)(dinv + N);             // N ints
    int*   csr    = cursor + N;                   // E ints
    int*   order  = csr + E;                      // N ints (degree-sorted node order)
    h8*    bufA   = (h8*)(order + N);             // N*6 h8
    h8*    bufC   = bufA + (size_t)N*6;           // N*6 h8
    float* partial= (float*)(bufC + (size_t)N*6); // KS*G*H floats (dedicated — no aliasing)
    float* scratch= partial + (size_t)KS*G*H;
    int*   pairs  = (int*)scratch;                // E ints (packed; CSR build)
    int*   cnt_t  = pairs + E;                    // NBLK1*NB ints

    // ---- kernel 1: bucket count + head split-K GEMM (independent, merged) ----
    k_bcnt_head<<<NBLK1 + (G/GB)*KS, TPB, 0, stream>>>(
        ei + E, cnt_t, E, NB, chunk, feature, Wf1, partial, G, FEAT, H);

    // ---- CSR build ----
    k_bscatter<<<NBLK1, TPB, 0, stream>>>(ei, cnt_t, pairs, E, NB, chunk);
    k_build   <<<NB, TPB, 0, stream>>>(pairs, cnt_t, csr, cursor, dinv, order, N, E, NB);

    // ---- conv1: bufA = dinv.*(x@W1) ; bufC = dinv.*relu(dinv*agg + b1) ----
    k_gemm1r <<<cdiv((long long)NRG*6, TPB), TPB, 0, stream>>>(x, W1, bufA, N, dinv);
    k_gather8<<<2048, TPB, 0, stream>>>(cursor, csr, order, bufA, dinv, b1, bufC, N, 1);

    // ---- conv2 + conv3-transform fused ----
    k_gconv2 <<<cdiv(N, NPB), TPB, 0, stream>>>(cursor, csr, bufC, dinv, W2, b2, W3, bufA, N);

    // ---- conv3 aggregate: bufC = relu(dinv*agg(bufA) + b3) ----
    k_gather8<<<2048, TPB, 0, stream>>>(cursor, csr, order, bufA, dinv, b3, bufC, N, 0);

    // ---- head epilogue: pool + combine ----
    k_headfin<<<G/4, 256, 0, stream>>>(partial, bf1, Wf2, bf2, bufC, batch,
                                       Wg, bg, out, G, H, N);
}

// Round 18
// 321.520 us; speedup vs baseline: 1.0326x; 1.0326x over previous
//
#include <hip/hip_runtime.h>
#include <hip/hip_fp16.h>

#define TPB 256
#define NBLK1 256          // CSR pass-1 blocks
#define BSH 10             // bucket shift: 1024 nodes per bucket (NB <= 128)
#define MAXBE 12288        // max edges/bucket -> 48KB LDS
#define KS 8               // head GEMM K-splits
#define GB 8               // head GEMM graphs per block
#define NPB 42             // gconv2 nodes/block (42*6 = 252 <= 256)

static inline int cdiv(long long a, int b){ return (int)((a + b - 1)/b); }

// 8 halves = 16 bytes, 16-byte aligned -> single dwordx4 loads
struct __align__(16) h8 { __half2 a, b, c, d; };
struct float8 { float4 lo, hi; };
__device__ inline float8 h8tof8(h8 v){
    float2 t0 = __half22float2(v.a), t1 = __half22float2(v.b);
    float2 t2 = __half22float2(v.c), t3 = __half22float2(v.d);
    float8 r;
    r.lo = make_float4(t0.x, t0.y, t1.x, t1.y);
    r.hi = make_float4(t2.x, t2.y, t3.x, t3.y);
    return r;
}
__device__ inline h8 f8toh8(float8 v){
    h8 r;
    r.a = __floats2half2_rn(v.lo.x, v.lo.y); r.b = __floats2half2_rn(v.lo.z, v.lo.w);
    r.c = __floats2half2_rn(v.hi.x, v.hi.y); r.d = __floats2half2_rn(v.hi.z, v.hi.w);
    return r;
}
__device__ inline void f8acc(float8& a, float8 v){
    a.lo.x += v.lo.x; a.lo.y += v.lo.y; a.lo.z += v.lo.z; a.lo.w += v.lo.w;
    a.hi.x += v.hi.x; a.hi.y += v.hi.y; a.hi.z += v.hi.z; a.hi.w += v.hi.w;
}

// ---------- kernel 1: bucket count (blocks 0..NBLK1) + head split-K GEMM (rest) ----------
__global__ void k_bcnt_head(const int* __restrict__ dst, int* __restrict__ cnt_t,
                            int E, int NB, int chunk,
                            const float* __restrict__ feature, const float* __restrict__ Wf1,
                            float* __restrict__ partial, int G, int FEAT, int H){
    __shared__ int hist[128];
    __shared__ float sfeat[128*GB];
    int t = threadIdx.x;
    if(blockIdx.x < NBLK1){
        // ---- bucket count ----
        int blk = blockIdx.x;
        for(int i = t; i < NB; i += blockDim.x) hist[i] = 0;
        __syncthreads();
        int lo = blk*chunk, hi = min(E, lo + chunk);
        for(int e = lo + t; e < hi; e += blockDim.x)
            atomicAdd(&hist[dst[e] >> BSH], 1);
        __syncthreads();
        for(int b = t; b < NB; b += blockDim.x)
            cnt_t[blk*NB + b] = hist[b];
    } else {
        // ---- head split-K GEMM: partial[ks][g][h] ----
        int bid = (int)blockIdx.x - NBLK1;          // 0..1023
        int g0 = (bid & 127)*GB;
        int ks = bid >> 7;
        int Kc = (FEAT + KS - 1)/KS;
        int k0 = ks*Kc;
        int k1 = min(FEAT, k0 + Kc);
        int kc = k1 - k0;
        for(int idx = t; idx < GB*128; idx += 256){
            int gi = idx >> 7, kk = idx & 127;
            if(kk < kc) sfeat[kk*GB + gi] = feature[(size_t)(g0+gi)*FEAT + k0 + kk];
        }
        __syncthreads();
        int h  = t & 127;
        int gq = t >> 7;
        const float* wp = Wf1 + (size_t)k0*H + h;
        float4 a = {0.f,0.f,0.f,0.f};
        const float4* sf = (const float4*)(sfeat) + gq;
        for(int kk = 0; kk < kc; kk++){
            float w = wp[(size_t)kk*H];
            float4 f = sf[kk*2];
            a.x += f.x*w; a.y += f.y*w; a.z += f.z*w; a.w += f.w*w;
        }
        float* pp = partial + ((size_t)ks*G + g0 + gq*4)*H + h;
        pp[0] = a.x; pp[H] = a.y; pp[2*H] = a.z; pp[3*H] = a.w;
    }
}

// scatter with inline prefix: pairs[pos] = (local_dst<<17)|src  (needs N < 2^17)
__global__ void k_bscatter(const int* __restrict__ ei, const int* __restrict__ cnt_t,
                           int* __restrict__ pairs, int E, int NB, int chunk){
    __shared__ int cur[128];
    __shared__ int st[128];
    int blk = blockIdx.x;
    int t = threadIdx.x;
    int myp = 0, myt = 0;
    for(int b2 = 0; b2 < NBLK1; b2++){
        int v = (t < NB) ? cnt_t[b2*NB + t] : 0;
        myp += (b2 < blk) ? v : 0;
        myt += v;
    }
    if(t < NB){ cur[t] = myp; st[t] = myt; }
    __syncthreads();
    if(t == 0){
        int run = 0;
        for(int b = 0; b < NB; b++){ int v = st[b]; st[b] = run; run += v; }
    }
    __syncthreads();
    if(t < NB) cur[t] += st[t];
    __syncthreads();
    int lo = blk*chunk, hi = min(E, lo + chunk);
    for(int e = lo + t; e < hi; e += blockDim.x){
        int s = ei[e], d = ei[E + e];
        int pos = atomicAdd(&cur[d >> BSH], 1);          // LDS atomic
        pairs[pos] = ((d & ((1 << BSH) - 1)) << 17) | s; // packed
    }
}

__global__ void k_build(const int* __restrict__ pairs, const int* __restrict__ cnt_t,
                        int* __restrict__ csr, int* __restrict__ cursor,
                        float* __restrict__ dinv, int N, int E, int NB){
    __shared__ int stot[128];
    __shared__ int sBase, sCnt;
    __shared__ int c[1024];
    __shared__ int so[1024];
    __shared__ int part[256];
    __shared__ int csrl[MAXBE];
    int b = blockIdx.x;
    int t = threadIdx.x;
    int myt = 0;
    for(int b2 = 0; b2 < NBLK1; b2++)
        myt += (t < NB) ? cnt_t[b2*NB + t] : 0;
    if(t < NB) stot[t] = myt;
    __syncthreads();
    if(t == 0){
        int run = 0;
        for(int bb = 0; bb < NB; bb++){
            if(bb == b){ sBase = run; sCnt = stot[bb]; }
            run += stot[bb];
        }
    }
    __syncthreads();
    int base = sBase, cntE = sCnt;
    int n0 = b << BSH;
    int nn = min(1 << BSH, N - n0);

    for(int i = t; i < 1024; i += 256) c[i] = 0;
    __syncthreads();
    for(int i = t; i < cntE; i += 256)
        atomicAdd(&c[pairs[base + i] >> 17], 1);   // LDS atomic
    __syncthreads();
    int i0 = t*4;
    int l0 = c[i0], l1 = c[i0+1], l2 = c[i0+2], l3 = c[i0+3];
    part[t] = l0 + l1 + l2 + l3;
    __syncthreads();
    for(int off = 1; off < 256; off <<= 1){
        int u = (t >= off) ? part[t-off] : 0;
        __syncthreads();
        part[t] += u;
        __syncthreads();
    }
    int run = (t == 0) ? 0 : part[t-1];
    so[i0] = run; so[i0+1] = run + l0; so[i0+2] = run + l0 + l1; so[i0+3] = run + l0 + l1 + l2;
    __syncthreads();
    for(int i = t; i < nn; i += 256){
        int cc = c[i];
        cursor[n0 + i] = base + so[i] + cc;        // inclusive end offset
        dinv[n0 + i]   = rsqrtf((float)(cc + 1));  // +1 = self-loop
    }
    for(int i = t; i < 1024; i += 256) c[i] = so[i];
    __syncthreads();
    for(int i = t; i < cntE; i += 256){
        int v = pairs[base + i];
        int pos = atomicAdd(&c[v >> 17], 1);       // LDS atomic
        csrl[pos] = v & 0x1FFFF;
    }
    __syncthreads();
    for(int i = t; i < cntE; i += 256) csr[base + i] = csrl[i];   // coalesced
}

// ---------- gather core: self + neighbor sum of one 16B chunk ----------
__device__ inline float8 gather_row(const int* __restrict__ cursor,
                                    const int* __restrict__ csr,
                                    const h8* __restrict__ t, int d, int cg){
    int start = (d == 0) ? 0 : cursor[d-1];
    int end   = cursor[d];
    float8 a0 = h8tof8(t[(size_t)d*6 + cg]);     // self-loop
    float8 a1 = {{0,0,0,0},{0,0,0,0}}, a2 = a1, a3 = a1;
    int j = start;
    for(; j + 8 <= end; j += 8){
        int s0 = csr[j],   s1 = csr[j+1], s2 = csr[j+2], s3 = csr[j+3];
        int s4 = csr[j+4], s5 = csr[j+5], s6 = csr[j+6], s7 = csr[j+7];
        h8 r0 = t[(size_t)s0*6 + cg];            // 8 independent dwordx4 in flight
        h8 r1 = t[(size_t)s1*6 + cg];
        h8 r2 = t[(size_t)s2*6 + cg];
        h8 r3 = t[(size_t)s3*6 + cg];
        h8 r4 = t[(size_t)s4*6 + cg];
        h8 r5 = t[(size_t)s5*6 + cg];
        h8 r6 = t[(size_t)s6*6 + cg];
        h8 r7 = t[(size_t)s7*6 + cg];
        f8acc(a0, h8tof8(r0)); f8acc(a1, h8tof8(r1));
        f8acc(a2, h8tof8(r2)); f8acc(a3, h8tof8(r3));
        f8acc(a0, h8tof8(r4)); f8acc(a1, h8tof8(r5));
        f8acc(a2, h8tof8(r6)); f8acc(a3, h8tof8(r7));
    }
    for(; j + 4 <= end; j += 4){
        int s0 = csr[j], s1 = csr[j+1], s2 = csr[j+2], s3 = csr[j+3];
        h8 r0 = t[(size_t)s0*6 + cg];
        h8 r1 = t[(size_t)s1*6 + cg];
        h8 r2 = t[(size_t)s2*6 + cg];
        h8 r3 = t[(size_t)s3*6 + cg];
        f8acc(a0, h8tof8(r0)); f8acc(a1, h8tof8(r1));
        f8acc(a2, h8tof8(r2)); f8acc(a3, h8tof8(r3));
    }
    for(; j < end; j++) f8acc(a0, h8tof8(t[(size_t)csr[j]*6 + cg]));
    f8acc(a0, a1); f8acc(a2, a3); f8acc(a0, a2);
    return a0;
}

// ---------- conv1 GEMM, row-batched x4: t = dinv .* (x @ W1) ----------
__global__ void k_gemm1r(const float* __restrict__ x, const float* __restrict__ W,
                         h8* __restrict__ t, int n, const float* __restrict__ dinv){
    __shared__ float sW[44*48];                   // [k][48], zero-padded cols
    for(int i = threadIdx.x; i < 44*48; i += blockDim.x){
        int k = i/48, j = i - k*48;
        sW[i] = (j < 44) ? W[k*44 + j] : 0.f;
    }
    __syncthreads();
    int nrg = (n + 3) >> 2;
    unsigned total = (unsigned)nrg * 6u;
    unsigned idx = blockIdx.x*blockDim.x + threadIdx.x;
    if(idx >= total) return;
    unsigned rg = idx / 6u;
    unsigned cg = idx - rg*6u;
    int row0 = (int)rg*4;
    const float4* sWv = (const float4*)sW;        // 12 float4 per k
    float8 acc[4] = {{{0,0,0,0},{0,0,0,0}},{{0,0,0,0},{0,0,0,0}},
                     {{0,0,0,0},{0,0,0,0}},{{0,0,0,0},{0,0,0,0}}};
    for(int k4 = 0; k4 < 11; k4++){
        float fv[4][4];
        #pragma unroll
        for(int r = 0; r < 4; r++){
            int rr = min(row0 + r, n - 1);        // clamp (tail rows duplicate, store guarded)
            *(float4*)fv[r] = ((const float4*)(x + (size_t)rr*44))[k4];
        }
        int kb = k4*4;
        #pragma unroll
        for(int i = 0; i < 4; i++){
            float4 wlo = sWv[(unsigned)(kb+i)*12 + cg*2];
            float4 whi = sWv[(unsigned)(kb+i)*12 + cg*2 + 1];
            #pragma unroll
            for(int r = 0; r < 4; r++){
                float h = fv[r][i];
                acc[r].lo.x += h*wlo.x; acc[r].lo.y += h*wlo.y;
                acc[r].lo.z += h*wlo.z; acc[r].lo.w += h*wlo.w;
                acc[r].hi.x += h*whi.x; acc[r].hi.y += h*whi.y;
                acc[r].hi.z += h*whi.z; acc[r].hi.w += h*whi.w;
            }
        }
    }
    #pragma unroll
    for(int r = 0; r < 4; r++){
        int row = row0 + r;
        if(row < n){
            float dd = dinv[row];
            acc[r].lo.x *= dd; acc[r].lo.y *= dd; acc[r].lo.z *= dd; acc[r].lo.w *= dd;
            acc[r].hi.x *= dd; acc[r].hi.y *= dd; acc[r].hi.z *= dd; acc[r].hi.w *= dd;
            t[(size_t)row*6 + cg] = f8toh8(acc[r]);
        }
    }
}

// ---------- plain gather: out = [prescale][relu-if-bias](dinv*agg [+ bias]) ----------
__global__ void k_gather8(const int* __restrict__ cursor, const int* __restrict__ csr,
                          const h8* __restrict__ t, const float* __restrict__ dinv,
                          const float* __restrict__ bias, h8* __restrict__ out,
                          int n, int prescale_out){
    __shared__ float sb[48];
    if(threadIdx.x < 48) sb[threadIdx.x] = (bias && threadIdx.x < 44) ? bias[threadIdx.x] : 0.f;
    __syncthreads();
    unsigned total  = (unsigned)n * 6u;
    unsigned stride = gridDim.x * blockDim.x;
    const float4* sb4 = (const float4*)sb;
    for(unsigned idx = blockIdx.x*blockDim.x + threadIdx.x; idx < total; idx += stride){
        unsigned d  = idx / 6u;
        unsigned cg = idx - d*6u;
        float8 acc = gather_row(cursor, csr, t, (int)d, (int)cg);
        float dd = dinv[d];
        float4 blo = sb4[cg*2], bhi = sb4[cg*2+1];
        acc.lo.x = acc.lo.x*dd + blo.x; acc.lo.y = acc.lo.y*dd + blo.y;
        acc.lo.z = acc.lo.z*dd + blo.z; acc.lo.w = acc.lo.w*dd + blo.w;
        acc.hi.x = acc.hi.x*dd + bhi.x; acc.hi.y = acc.hi.y*dd + bhi.y;
        acc.hi.z = acc.hi.z*dd + bhi.z; acc.hi.w = acc.hi.w*dd + bhi.w;
        if(bias){
            acc.lo.x = fmaxf(acc.lo.x, 0.f); acc.lo.y = fmaxf(acc.lo.y, 0.f);
            acc.lo.z = fmaxf(acc.lo.z, 0.f); acc.lo.w = fmaxf(acc.lo.w, 0.f);
            acc.hi.x = fmaxf(acc.hi.x, 0.f); acc.hi.y = fmaxf(acc.hi.y, 0.f);
            acc.hi.z = fmaxf(acc.hi.z, 0.f); acc.hi.w = fmaxf(acc.hi.w, 0.f);
        }
        if(prescale_out){
            acc.lo.x *= dd; acc.lo.y *= dd; acc.lo.z *= dd; acc.lo.w *= dd;
            acc.hi.x *= dd; acc.hi.y *= dd; acc.hi.z *= dd; acc.hi.w *= dd;
        }
        out[(size_t)d*6 + cg] = f8toh8(acc);
    }
}

// ---------- fused conv2 + conv3-transform (round-14 structure — do not touch) ----------
__global__ void k_gconv2(const int* __restrict__ cursor, const int* __restrict__ csr,
                         const h8* __restrict__ tin, const float* __restrict__ dinv,
                         const float* __restrict__ W2, const float* __restrict__ b2,
                         const float* __restrict__ W3, h8* __restrict__ tout, int N){
    __shared__ float sW[44*88];     // W2 [44][88]; later reused for W3 [88][44]
    __shared__ float sb2[88];
    __shared__ float sAgg[NPB*49];
    __shared__ float sH2[NPB*89];
    __shared__ float sDinv[NPB];
    int t  = threadIdx.x;
    int d0 = blockIdx.x*NPB;
    int nn = min(NPB, N - d0);

    for(int i = t; i < 44*88; i += 256) sW[i] = W2[i];
    if(t < 88) sb2[t] = b2[t];
    __syncthreads();

    // phase 1: gather (6 threads per node)
    int ln = t/6, c = t - ln*6;
    if(t < NPB*6 && ln < nn){
        int d = d0 + ln;
        float8 acc = gather_row(cursor, csr, tin, d, c);
        float dd = dinv[d];
        if(c == 0) sDinv[ln] = dd;
        float* ar = sAgg + ln*49 + c*8;
        ar[0] = acc.lo.x*dd; ar[1] = acc.lo.y*dd; ar[2] = acc.lo.z*dd; ar[3] = acc.lo.w*dd;
        ar[4] = acc.hi.x*dd; ar[5] = acc.hi.y*dd; ar[6] = acc.hi.z*dd; ar[7] = acc.hi.w*dd;
    }
    __syncthreads();

    // phase 2: h2 = relu(t2 @ W2 + b2), float4-col chunks (22 per node)
    {
        const float4* sW4  = (const float4*)sW;    // 22 float4 per k
        const float4* sb24 = (const float4*)sb2;
        for(int o = t; o < nn*22; o += 256){
            int n_ = o/22, c4 = o - n_*22;
            const float* ar = sAgg + n_*49;
            float4 s = sb24[c4];
            for(int k = 0; k < 44; k++){
                float a = ar[k];
                float4 w = sW4[(unsigned)k*22 + c4];
                s.x += a*w.x; s.y += a*w.y; s.z += a*w.z; s.w += a*w.w;
            }
            float* hp = sH2 + n_*89 + c4*4;        // scalar stores (odd stride)
            hp[0] = fmaxf(s.x, 0.f); hp[1] = fmaxf(s.y, 0.f);
            hp[2] = fmaxf(s.z, 0.f); hp[3] = fmaxf(s.w, 0.f);
        }
    }
    __syncthreads();
    // restage W3 (88 x 44)
    for(int i = t; i < 88*44; i += 256) sW[i] = W3[i];
    __syncthreads();

    // phase 3: t3 = dinv * (h2 @ W3); one h8 chunk per thread
    {
        const float4* sW4 = (const float4*)sW;     // 11 float4 per k
        for(int o = t; o < nn*6; o += 256){
            int n_ = o/6, cc = o - n_*6;
            const float* hr = sH2 + n_*89;
            float dd = sDinv[n_];
            float4 slo = {0,0,0,0}, shi = {0,0,0,0};
            if(cc < 5){
                for(int k = 0; k < 88; k++){
                    float h = hr[k];
                    float4 wlo = sW4[(unsigned)k*11 + cc*2];
                    float4 whi = sW4[(unsigned)k*11 + cc*2 + 1];
                    slo.x += h*wlo.x; slo.y += h*wlo.y; slo.z += h*wlo.z; slo.w += h*wlo.w;
                    shi.x += h*whi.x; shi.y += h*whi.y; shi.z += h*whi.z; shi.w += h*whi.w;
                }
            } else {                                // cols 40..43 valid, 44..47 pad=0
                for(int k = 0; k < 88; k++){
                    float h = hr[k];
                    float4 wlo = sW4[(unsigned)k*11 + 10];
                    slo.x += h*wlo.x; slo.y += h*wlo.y; slo.z += h*wlo.z; slo.w += h*wlo.w;
                }
            }
            float8 acc;
            acc.lo = make_float4(slo.x*dd, slo.y*dd, slo.z*dd, slo.w*dd);
            acc.hi = make_float4(shi.x*dd, shi.y*dd, shi.z*dd, shi.w*dd);
            tout[(size_t)(d0+n_)*6 + cc] = f8toh8(acc);
        }
    }
}

// fused pool + epilogue: 4 graphs/block (one wave each).
__global__ void k_headfin(const float* __restrict__ partial, const float* __restrict__ bf1,
                          const float* __restrict__ Wf2, const float* __restrict__ bf2,
                          const h8* __restrict__ hbuf, const int* __restrict__ batch,
                          const float* __restrict__ Wg, const float* __restrict__ bg,
                          float* __restrict__ out, int G, int H, int n){
    int g    = blockIdx.x*4 + (threadIdx.x >> 6);
    int lane = threadIdx.x & 63;

    // segment bounds (batch sorted, non-empty)
    int lo = 0, hi = n;
    while(lo < hi){ int mid = (lo + hi) >> 1; if(batch[mid] < g) lo = mid + 1; else hi = mid; }
    int start = lo;
    hi = n;
    while(lo < hi){ int mid = (lo + hi) >> 1; if(batch[mid] < g + 1) lo = mid + 1; else hi = mid; }
    int end = lo;

    int rg = lane >> 3;          // 0..7 row groups
    int cg = lane & 7;           // 0..7 chunk slots, active < 6
    float8 m = {{0,0,0,0},{0,0,0,0}};    // valid floor: post-ReLU inputs
    if(cg < 6){
        for(int r = start + rg; r < end; r += 8){
            float8 v = h8tof8(hbuf[(size_t)r*6 + cg]);
            m.lo.x = fmaxf(m.lo.x, v.lo.x); m.lo.y = fmaxf(m.lo.y, v.lo.y);
            m.lo.z = fmaxf(m.lo.z, v.lo.z); m.lo.w = fmaxf(m.lo.w, v.lo.w);
            m.hi.x = fmaxf(m.hi.x, v.hi.x); m.hi.y = fmaxf(m.hi.y, v.hi.y);
            m.hi.z = fmaxf(m.hi.z, v.hi.z); m.hi.w = fmaxf(m.hi.w, v.hi.w);
        }
    }
    for(int off = 8; off <= 32; off <<= 1){
        m.lo.x = fmaxf(m.lo.x, __shfl_xor(m.lo.x, off, 64));
        m.lo.y = fmaxf(m.lo.y, __shfl_xor(m.lo.y, off, 64));
        m.lo.z = fmaxf(m.lo.z, __shfl_xor(m.lo.z, off, 64));
        m.lo.w = fmaxf(m.lo.w, __shfl_xor(m.lo.w, off, 64));
        m.hi.x = fmaxf(m.hi.x, __shfl_xor(m.hi.x, off, 64));
        m.hi.y = fmaxf(m.hi.y, __shfl_xor(m.hi.y, off, 64));
        m.hi.z = fmaxf(m.hi.z, __shfl_xor(m.hi.z, off, 64));
        m.hi.w = fmaxf(m.hi.w, __shfl_xor(m.hi.w, off, 64));
    }
    // x1 partial dot (only rg==0 lanes contribute; cols 44..47 are pad)
    float v = 0.f;
    if(rg == 0 && cg < 6){
        int base = cg*8;
        v = m.lo.x*Wg[base] + m.lo.y*Wg[base+1] + m.lo.z*Wg[base+2] + m.lo.w*Wg[base+3];
        if(cg < 5)
            v += m.hi.x*Wg[base+4] + m.hi.y*Wg[base+5] + m.hi.z*Wg[base+6] + m.hi.w*Wg[base+7];
    }

    // x2: combine split-K partials
    int h2 = lane;
    float2 s = {0.f, 0.f};
    for(int ks = 0; ks < KS; ks++){
        float2 p = ((const float2*)(partial + ((size_t)ks*G + g)*H))[h2];
        s.x += p.x; s.y += p.y;
    }
    float2 b  = ((const float2*)bf1)[h2];
    float2 w2 = ((const float2*)Wf2)[h2];
    float y = fmaxf(s.x + b.x, 0.f)*w2.x + fmaxf(s.y + b.y, 0.f)*w2.y;

    for(int off = 32; off; off >>= 1){
        y += __shfl_xor(y, off, 64);
        v += __shfl_xor(v, off, 64);
    }
    if(lane == 0) out[g] = fmaxf(v + bg[0], 0.f) + y + bf2[0];
}

extern "C" void kernel_launch(void* const* d_in, const int* in_sizes, int n_in,
                              void* d_out, int out_size, void* d_ws, size_t ws_size,
                              hipStream_t stream) {
    const float* x       = (const float*)d_in[0];
    const int*   ei      = (const int*)  d_in[1];
    const int*   batch   = (const int*)  d_in[2];
    const float* feature = (const float*)d_in[3];
    const float* W1 = (const float*)d_in[4];  const float* b1 = (const float*)d_in[5];
    const float* W2 = (const float*)d_in[6];  const float* b2 = (const float*)d_in[7];
    const float* W3 = (const float*)d_in[8];  const float* b3 = (const float*)d_in[9];
    const float* Wg = (const float*)d_in[10]; const float* bg = (const float*)d_in[11];
    const float* Wf1= (const float*)d_in[12]; const float* bf1= (const float*)d_in[13];
    const float* Wf2= (const float*)d_in[14]; const float* bf2= (const float*)d_in[15];
    float* out = (float*)d_out;

    const int N    = in_sizes[2];          // 100000 (< 2^17 required by pair packing)
    const int E    = in_sizes[1] / 2;      // 1000000
    const int G    = out_size;             // 1024
    const int FEAT = in_sizes[3] / G;      // 1019
    const int H    = in_sizes[13];         // 128

    const int NB    = cdiv(N, 1 << BSH);   // 98 coarse buckets
    const int chunk = cdiv(E, NBLK1);
    const int NRG   = cdiv(N, 4);

    // workspace layout (4B units)
    float* wsf    = (float*)d_ws;
    float* dinv   = wsf;                          // N floats
    int*   cursor = (int*)(dinv + N);             // N ints
    int*   csr    = cursor + N;                   // E ints
    h8*    bufA   = (h8*)(csr + E);               // N*6 h8
    h8*    bufC   = bufA + (size_t)N*6;           // N*6 h8
    float* partial= (float*)(bufC + (size_t)N*6); // KS*G*H floats (dedicated — no aliasing)
    float* scratch= partial + (size_t)KS*G*H;
    int*   pairs  = (int*)scratch;                // E ints (packed; CSR build)
    int*   cnt_t  = pairs + E;                    // NBLK1*NB ints

    // ---- kernel 1: bucket count + head split-K GEMM (independent, merged) ----
    k_bcnt_head<<<NBLK1 + (G/GB)*KS, TPB, 0, stream>>>(
        ei + E, cnt_t, E, NB, chunk, feature, Wf1, partial, G, FEAT, H);

    // ---- CSR build ----
    k_bscatter<<<NBLK1, TPB, 0, stream>>>(ei, cnt_t, pairs, E, NB, chunk);
    k_build   <<<NB, TPB, 0, stream>>>(pairs, cnt_t, csr, cursor, dinv, N, E, NB);

    // ---- conv1: bufA = dinv.*(x@W1) ; bufC = dinv.*relu(dinv*agg + b1) ----
    k_gemm1r <<<cdiv((long long)NRG*6, TPB), TPB, 0, stream>>>(x, W1, bufA, N, dinv);
    k_gather8<<<2048, TPB, 0, stream>>>(cursor, csr, bufA, dinv, b1, bufC, N, 1);

    // ---- conv2 + conv3-transform fused ----
    k_gconv2 <<<cdiv(N, NPB), TPB, 0, stream>>>(cursor, csr, bufC, dinv, W2, b2, W3, bufA, N);

    // ---- conv3 aggregate: bufC = relu(dinv*agg(bufA) + b3) ----
    k_gather8<<<2048, TPB, 0, stream>>>(cursor, csr, bufA, dinv, b3, bufC, N, 0);

    // ---- head epilogue: pool + combine ----
    k_headfin<<<G/4, 256, 0, stream>>>(partial, bf1, Wf2, bf2, bufC, batch,
                                       Wg, bg, out, G, H, N);
}